// Round 10
// baseline (220.880 us; speedup 1.0000x reference)
//
#include <hip/hip_runtime.h>
#include <cstdint>

typedef _Float16 half2_t __attribute__((ext_vector_type(2)));
typedef _Float16 half4_t __attribute__((ext_vector_type(4)));
typedef _Float16 half8_t __attribute__((ext_vector_type(8)));
typedef float floatx4 __attribute__((ext_vector_type(4)));

#define T_SEQ 4096
#define D_HEAD 128
#define SCALE_LOG2 0.12751742526f  // log2(e)/sqrt(128), folded into q at proj time

__device__ __forceinline__ void gload16(const void* src, void* dst_lds) {
    using gptr_t = const __attribute__((address_space(1))) unsigned int*;
    using lptr_t = __attribute__((address_space(3))) unsigned int*;
    __builtin_amdgcn_global_load_lds((gptr_t)(uintptr_t)src,
                                     (lptr_t)(unsigned int)(uintptr_t)dst_lds, 16, 0, 0);
}

__device__ __forceinline__ float exp2_raw(float x) {
#if __has_builtin(__builtin_amdgcn_exp2f)
    return __builtin_amdgcn_exp2f(x);   // raw v_exp_f32
#else
    return exp2f(x);
#endif
}

// ---------------- QKV projection (MFMA f16, fp32 accumulate) ----------------
__global__ __launch_bounds__(256) void proj_kernel(
    const float* __restrict__ x,
    const float* __restrict__ Wq, const float* __restrict__ bq,
    const float* __restrict__ Wk, const float* __restrict__ bk,
    const float* __restrict__ Wv, const float* __restrict__ bv,
    _Float16* __restrict__ qf, _Float16* __restrict__ kf, _Float16* __restrict__ vt)
{
    __shared__ __align__(16) _Float16 Ws[128 * 136];
    __shared__ __align__(16) _Float16 xs[64 * 136];

    const int t = threadIdx.x;
    const int mat = blockIdx.y;
    const float* W = (mat == 0) ? Wq : (mat == 1) ? Wk : Wv;
    const float* bias = (mat == 0) ? bq : (mat == 1) ? bk : bv;
    const float osc = (mat == 0) ? SCALE_LOG2 : 1.0f;
    const int r0 = blockIdx.x * 64;

    {
        const int o = t >> 1;
        const int i0 = (t & 1) * 64;
        for (int jj = 0; jj < 8; ++jj) {
            floatx4 w0 = *reinterpret_cast<const floatx4*>(W + o * 128 + i0 + jj * 8);
            floatx4 w1 = *reinterpret_cast<const floatx4*>(W + o * 128 + i0 + jj * 8 + 4);
            half8_t h;
            h[0]=(_Float16)w0[0]; h[1]=(_Float16)w0[1]; h[2]=(_Float16)w0[2]; h[3]=(_Float16)w0[3];
            h[4]=(_Float16)w1[0]; h[5]=(_Float16)w1[1]; h[6]=(_Float16)w1[2]; h[7]=(_Float16)w1[3];
            *reinterpret_cast<half8_t*>(&Ws[o * 136 + i0 + jj * 8]) = h;
        }
    }
    {
        const int row = t >> 2;
        const int c0 = (t & 3) * 32;
        for (int jj = 0; jj < 4; ++jj) {
            floatx4 w0 = *reinterpret_cast<const floatx4*>(x + (size_t)(r0 + row) * 128 + c0 + jj * 8);
            floatx4 w1 = *reinterpret_cast<const floatx4*>(x + (size_t)(r0 + row) * 128 + c0 + jj * 8 + 4);
            half8_t h;
            h[0]=(_Float16)w0[0]; h[1]=(_Float16)w0[1]; h[2]=(_Float16)w0[2]; h[3]=(_Float16)w0[3];
            h[4]=(_Float16)w1[0]; h[5]=(_Float16)w1[1]; h[6]=(_Float16)w1[2]; h[7]=(_Float16)w1[3];
            *reinterpret_cast<half8_t*>(&xs[row * 136 + c0 + jj * 8]) = h;
        }
    }
    __syncthreads();

    const int w = t >> 6;
    const int lane = t & 63;
    const int lo = lane & 15, hi = lane >> 4;

    floatx4 acc[8] = {};
    for (int dc = 0; dc < 4; ++dc) {
        half8_t a8 = *reinterpret_cast<const half8_t*>(&xs[(w * 16 + lo) * 136 + dc * 32 + hi * 8]);
        for (int ot = 0; ot < 8; ++ot) {
            half8_t b8 = *reinterpret_cast<const half8_t*>(&Ws[(ot * 16 + lo) * 136 + dc * 32 + hi * 8]);
            acc[ot] = __builtin_amdgcn_mfma_f32_16x16x32_f16(a8, b8, acc[ot], 0, 0, 0);
        }
    }
    __syncthreads();

    float bb[8];
    for (int ot = 0; ot < 8; ++ot) bb[ot] = bias[ot * 16 + lo];

    if (mat < 2) {
        _Float16* ol = xs;
        for (int ot = 0; ot < 8; ++ot)
            for (int r = 0; r < 4; ++r)
                ol[(w * 16 + hi * 4 + r) * 136 + ot * 16 + lo] = (_Float16)((acc[ot][r] + bb[ot]) * osc);
        __syncthreads();
        _Float16* dst = (mat == 0) ? qf : kf;
        for (int i = 0; i < 4; ++i) {
            int c = t + 256 * i;
            int row = c >> 4, p = c & 15;
            half8_t v = *reinterpret_cast<const half8_t*>(&ol[row * 136 + p * 8]);
            *reinterpret_cast<half8_t*>(dst + (size_t)(r0 + row) * 128 + p * 8) = v;
        }
    } else {
        _Float16* vl = Ws;  // [128][72]
        for (int ot = 0; ot < 8; ++ot)
            for (int r = 0; r < 4; ++r)
                vl[(ot * 16 + lo) * 72 + w * 16 + hi * 4 + r] = (_Float16)(acc[ot][r] + bb[ot]);
        __syncthreads();
        const int b = r0 >> 12, tl0 = r0 & 4095;
        for (int i = 0; i < 4; ++i) {
            int c = t + 256 * i;
            int d = c >> 3, p = c & 7;
            half8_t v = *reinterpret_cast<const half8_t*>(&vl[d * 72 + p * 8]);
            *reinterpret_cast<half8_t*>(vt + ((size_t)(b * 128 + d)) * 4096 + tl0 + p * 8) = v;
        }
    }
}

// ---------------- flash attention ----------------
// 256 blocks x 512 threads = 8 waves = 8 kv-splits; EACH wave covers all 64 q rows
// (4 q-tiles of 16) x its 16 kv of a 128-kv tile -> every staged K/V byte is read
// exactly once (dup=1). K+V double-buffered: 2 x (K 32KB + V 32KB) = 128KB LDS.
// Per tile: [issue K(i+1) glds + V(i+1)->regs] [QK(i)] [defer] [PV(i-1)] [barA]
//           [V(i+1) reg->LDS] [softmax pa(i)] [barB].  (PV(i-1) must drain before
//           V(i+1) overwrites its buffer -> 2 barriers/tile.)
__global__ __launch_bounds__(512, 1) void attn_kernel(
    const _Float16* __restrict__ qf, const _Float16* __restrict__ kf,
    const _Float16* __restrict__ vt, float* __restrict__ out)
{
    __shared__ __align__(16) char smem[131072];  // buf i at i*65536: [K 32KB][V 32KB]

    const int tid = threadIdx.x;
    const int w = tid >> 6, lane = tid & 63;     // w = kv-split 0..7
    const int lo = lane & 15, hi = lane >> 4;

    // XCD-aware swizzle: 32 consecutive wg per XCD -> one batch's K/V per XCD L2
    const int bx = blockIdx.x;
    const int wg = (bx & 7) * 32 + (bx >> 3);
    const int b = wg >> 6;
    const int q0 = (wg & 63) * 64;

    const char* kbc = (const char*)(kf + (size_t)b * T_SEQ * 128);
    const char* vbc = (const char*)(vt + (size_t)b * 128 * T_SEQ);

    // K staging: 4 gload16/thread (32KB tile). LDS[row][slot] = K[row][slot ^ (row&7)]
    int koff[4], kdst[4];
#pragma unroll
    for (int r = 0; r < 4; ++r) {
        int seg = w * 4 + r;                 // 0..31, each seg = 4 rows = 1KB
        int slot = lane & 15;
        int row = seg * 4 + (lane >> 4);
        koff[r] = row * 256 + ((slot ^ (row & 7)) << 4);
        kdst[r] = seg * 1024 + lane * 16;
    }
    // V staging (reg->LDS): thread owns d = tid>>2, 64B quarter (tid&3) of the 256B
    // tile-row. LDS[d][slot] = Vchunk[slot ^ (d&7)] (16 chunks of 16B per row).
    const int vd = tid >> 2, vq = tid & 3;
    int vglob[4], vwds[4];
#pragma unroll
    for (int i = 0; i < 4; ++i) {
        int c = vq * 4 + i;
        vglob[i] = vd * (T_SEQ * 2) + c * 16;
        vwds[i] = 32768 + vd * 256 + ((c ^ (vd & 7)) << 4);
    }
    // LDS read offsets (loop-invariant)
    int kro[4];
#pragma unroll
    for (int dc = 0; dc < 4; ++dc)
        kro[dc] = (w * 16 + lo) * 256 + (((dc * 4 + hi) ^ (lo & 7)) << 4);
    int vro[8];
#pragma unroll
    for (int dt = 0; dt < 8; ++dt)
        vro[dt] = 32768 + (dt * 16 + lo) * 256 +
                  (((w * 2 + (hi >> 1)) ^ (lo & 7)) << 4) + ((hi & 1) << 3);

    // Q fragments: 4 q-tiles x 4 dc (pre-scaled; d-enum dc*32+hi*8+j matches K-side)
    half8_t qfrag[4][4];
#pragma unroll
    for (int qt = 0; qt < 4; ++qt) {
        const _Float16* qrow = qf + ((size_t)b * T_SEQ + q0 + qt * 16 + lo) * 128;
#pragma unroll
        for (int dc = 0; dc < 4; ++dc)
            qfrag[qt][dc] = *reinterpret_cast<const half8_t*>(qrow + dc * 32 + hi * 8);
    }

    floatx4 accO[4][8] = {};                      // [qt][dt], fp32
    float m[4] = {-1e30f, -1e30f, -1e30f, -1e30f};
    float l[4] = {};                              // LANE-PARTIAL
    half4_t pa[4] = {};                           // P of previous tile

    // prologue: K(0), V(0) -> buf0
#pragma unroll
    for (int r = 0; r < 4; ++r) gload16(kbc + koff[r], smem + kdst[r]);
#pragma unroll
    for (int i = 0; i < 4; ++i) {
        uint4 v = *reinterpret_cast<const uint4*>(vbc + vglob[i]);
        *reinterpret_cast<uint4*>(smem + vwds[i]) = v;
    }
    __syncthreads();

#define TILE(T0, CUR, NXT, PF, DOPREV) do {                                            \
    uint4 vr[4];                                                                       \
    if (PF) {                                                                          \
        const char* ks = kbc + (size_t)((T0) + 128) * 256;                             \
        _Pragma("unroll")                                                              \
        for (int r = 0; r < 4; ++r) gload16(ks + koff[r], smem + (NXT) + kdst[r]);     \
        const char* vs = vbc + (size_t)((T0) + 128) * 2;                               \
        _Pragma("unroll")                                                              \
        for (int i = 0; i < 4; ++i)                                                    \
            vr[i] = *reinterpret_cast<const uint4*>(vs + vglob[i]);                    \
    }                                                                                  \
    floatx4 sac[4] = {};                                                               \
    __builtin_amdgcn_s_setprio(1);                                                     \
    _Pragma("unroll")                                                                  \
    for (int dc = 0; dc < 4; ++dc) {                                                   \
        half8_t kf8 = *reinterpret_cast<const half8_t*>(smem + (CUR) + kro[dc]);       \
        _Pragma("unroll")                                                              \
        for (int qt = 0; qt < 4; ++qt)                                                 \
            sac[qt] = __builtin_amdgcn_mfma_f32_16x16x32_f16(kf8, qfrag[qt][dc], sac[qt], 0, 0, 0); \
    }                                                                                  \
    __builtin_amdgcn_s_setprio(0);                                                     \
    bool ok = true;                                                                    \
    float mp[4];                                                                       \
    _Pragma("unroll")                                                                  \
    for (int qt = 0; qt < 4; ++qt) {                                                   \
        mp[qt] = fmaxf(fmaxf(sac[qt][0], sac[qt][1]), fmaxf(sac[qt][2], sac[qt][3]));  \
        ok = ok && (mp[qt] <= m[qt] + 4.0f);                                           \
    }                                                                                  \
    if (!__all(ok)) {                                                                  \
        _Pragma("unroll")                                                              \
        for (int qt = 0; qt < 4; ++qt) {                                               \
            float r = mp[qt];                                                          \
            r = fmaxf(r, __shfl_xor(r, 16)); r = fmaxf(r, __shfl_xor(r, 32));          \
            float n = fmaxf(m[qt], r);                                                 \
            float a = exp2_raw(m[qt] - n);                                             \
            l[qt] *= a;                                                                \
            _Pragma("unroll")                                                          \
            for (int dt = 0; dt < 8; ++dt) accO[qt][dt] *= a;                          \
            m[qt] = n;                                                                 \
        }                                                                              \
    }                                                                                  \
    if (DOPREV) {                                                                      \
        __builtin_amdgcn_s_setprio(1);                                                 \
        _Pragma("unroll")                                                              \
        for (int dt = 0; dt < 8; ++dt) {                                               \
            half4_t vfr = *reinterpret_cast<const half4_t*>(smem + (NXT) + vro[dt]);   \
            _Pragma("unroll")                                                          \
            for (int qt = 0; qt < 4; ++qt)                                             \
                accO[qt][dt] = __builtin_amdgcn_mfma_f32_16x16x16f16(vfr, pa[qt], accO[qt][dt], 0, 0, 0); \
        }                                                                              \
        __builtin_amdgcn_s_setprio(0);                                                 \
    }                                                                                  \
    __syncthreads();  /* barA: PV reads of V(i-1) done before overwrite */             \
    if (PF) {                                                                          \
        _Pragma("unroll")                                                              \
        for (int i = 0; i < 4; ++i)                                                    \
            *reinterpret_cast<uint4*>(smem + (NXT) + vwds[i]) = vr[i];                 \
    }                                                                                  \
    _Pragma("unroll")                                                                  \
    for (int qt = 0; qt < 4; ++qt) {                                                   \
        float p0 = exp2_raw(sac[qt][0] - m[qt]), p1 = exp2_raw(sac[qt][1] - m[qt]);    \
        float p2 = exp2_raw(sac[qt][2] - m[qt]), p3 = exp2_raw(sac[qt][3] - m[qt]);    \
        l[qt] += (p0 + p1) + (p2 + p3);                                                \
        half2_t h0 = __builtin_bit_cast(half2_t, __builtin_amdgcn_cvt_pkrtz(p0, p1));  \
        half2_t h1 = __builtin_bit_cast(half2_t, __builtin_amdgcn_cvt_pkrtz(p2, p3));  \
        pa[qt][0] = h0[0]; pa[qt][1] = h0[1]; pa[qt][2] = h1[0]; pa[qt][3] = h1[1];    \
    }                                                                                  \
    __syncthreads();  /* barB: staging (K glds via waitcnt, V writes) complete */      \
} while (0)

    // 32 tiles of 128 kv; buffers alternate 0 / 65536 by tile parity.
    TILE(0, 0, 65536, 1, 0);
    for (int tt = 128; tt < 3840; tt += 256) {
        TILE(tt,       65536, 0,     1, 1);
        TILE(tt + 128, 0,     65536, 1, 1);
    }
    TILE(3968, 65536, 0, 0, 1);
#undef TILE

    // epilogue: PV of tile 31 (V(3968) in buf1's V region, pa = P(3968))
#pragma unroll
    for (int dt = 0; dt < 8; ++dt) {
        half4_t vfr = *reinterpret_cast<const half4_t*>(smem + 65536 + vro[dt]);
#pragma unroll
        for (int qt = 0; qt < 4; ++qt)
            accO[qt][dt] = __builtin_amdgcn_mfma_f32_16x16x16f16(vfr, pa[qt], accO[qt][dt], 0, 0, 0);
    }

    // reduce lane-partial l across hi-groups (once)
#pragma unroll
    for (int qt = 0; qt < 4; ++qt) {
        l[qt] += __shfl_xor(l[qt], 16);
        l[qt] += __shfl_xor(l[qt], 32);
    }

    // ---- merge 8 kv-splits ----
    float* red_m = reinterpret_cast<float*>(smem + 65536);   // [8][64] (buf1-K dead)
    float* red_l = reinterpret_cast<float*>(smem + 67584);   // [8][64]
    __syncthreads();   // ensure epilogue PV reads done before overwriting buf1
    if (hi == 0) {
#pragma unroll
        for (int qt = 0; qt < 4; ++qt) {
            red_m[w * 64 + qt * 16 + lo] = m[qt];
            red_l[w * 64 + qt * 16 + lo] = l[qt];
        }
    }
    __syncthreads();
    float fac[4];
#pragma unroll
    for (int qt = 0; qt < 4; ++qt) {
        int row = qt * 16 + lo;
        float M = -1e30f, L = 0.f;
#pragma unroll
        for (int s = 0; s < 8; ++s) M = fmaxf(M, red_m[s * 64 + row]);
#pragma unroll
        for (int s = 0; s < 8; ++s) L += red_l[s * 64 + row] * exp2_raw(red_m[s * 64 + row] - M);
        fac[qt] = exp2_raw(m[qt] - M) / L;
    }
    float* out_lds = reinterpret_cast<float*>(smem);  // [64][132] fp32 (buf0 dead)
    for (int s = 0; s < 8; ++s) {
        if (w == s) {
#pragma unroll
            for (int qt = 0; qt < 4; ++qt)
#pragma unroll
                for (int dt = 0; dt < 8; ++dt)
#pragma unroll
                    for (int r = 0; r < 4; ++r) {
                        int d = dt * 16 + hi * 4 + r;
                        float v = accO[qt][dt][r] * fac[qt];
                        float* p = &out_lds[(qt * 16 + lo) * 132 + d];
                        if (s == 0) *p = v; else *p += v;
                    }
        }
        __syncthreads();
    }
    {
        int row = tid >> 3, d0 = (tid & 7) * 16;
        float* op = out + ((size_t)b * T_SEQ + q0 + row) * 128 + d0;
#pragma unroll
        for (int j = 0; j < 4; ++j) {
            float4 v;
            v.x = out_lds[row * 132 + d0 + j * 4 + 0];
            v.y = out_lds[row * 132 + d0 + j * 4 + 1];
            v.z = out_lds[row * 132 + d0 + j * 4 + 2];
            v.w = out_lds[row * 132 + d0 + j * 4 + 3];
            *reinterpret_cast<float4*>(op + j * 4) = v;
        }
    }
}

extern "C" void kernel_launch(void* const* d_in, const int* in_sizes, int n_in,
                              void* d_out, int out_size, void* d_ws, size_t ws_size,
                              hipStream_t stream)
{
    (void)in_sizes; (void)n_in; (void)out_size; (void)ws_size;
    const float* x  = (const float*)d_in[0];
    const float* Wq = (const float*)d_in[1];
    const float* bq = (const float*)d_in[2];
    const float* Wk = (const float*)d_in[3];
    const float* bk = (const float*)d_in[4];
    const float* Wv = (const float*)d_in[5];
    const float* bv = (const float*)d_in[6];
    float* out = (float*)d_out;

    _Float16* qf = (_Float16*)d_ws;
    _Float16* kf = qf + (size_t)4 * T_SEQ * D_HEAD;
    _Float16* vt = kf + (size_t)4 * T_SEQ * D_HEAD;

    proj_kernel<<<dim3(256, 3), 256, 0, stream>>>(x, Wq, bq, Wk, bk, Wv, bv, qf, kf, vt);
    attn_kernel<<<dim3(256), 512, 0, stream>>>(qf, kf, vt, out);
}

// Round 11
// 101.694 us; speedup vs baseline: 2.1720x; 2.1720x over previous
//
#include <hip/hip_runtime.h>
#include <cstdint>

typedef _Float16 half2_t __attribute__((ext_vector_type(2)));
typedef _Float16 half4_t __attribute__((ext_vector_type(4)));
typedef _Float16 half8_t __attribute__((ext_vector_type(8)));
typedef float floatx4 __attribute__((ext_vector_type(4)));

#define T_SEQ 4096
#define D_HEAD 128
#define SCALE_LOG2 0.12751742526f  // log2(e)/sqrt(128), folded into q at proj time

__device__ __forceinline__ void gload16(const void* src, void* dst_lds) {
    using gptr_t = const __attribute__((address_space(1))) unsigned int*;
    using lptr_t = __attribute__((address_space(3))) unsigned int*;
    __builtin_amdgcn_global_load_lds((gptr_t)(uintptr_t)src,
                                     (lptr_t)(unsigned int)(uintptr_t)dst_lds, 16, 0, 0);
}

__device__ __forceinline__ float exp2_raw(float x) {
#if __has_builtin(__builtin_amdgcn_exp2f)
    return __builtin_amdgcn_exp2f(x);   // raw v_exp_f32
#else
    return exp2f(x);
#endif
}

// ---------------- QKV projection (MFMA f16, fp32 accumulate) ----------------
__global__ __launch_bounds__(256) void proj_kernel(
    const float* __restrict__ x,
    const float* __restrict__ Wq, const float* __restrict__ bq,
    const float* __restrict__ Wk, const float* __restrict__ bk,
    const float* __restrict__ Wv, const float* __restrict__ bv,
    _Float16* __restrict__ qf, _Float16* __restrict__ kf, _Float16* __restrict__ vt)
{
    __shared__ __align__(16) _Float16 Ws[128 * 136];
    __shared__ __align__(16) _Float16 xs[64 * 136];

    const int t = threadIdx.x;
    const int mat = blockIdx.y;
    const float* W = (mat == 0) ? Wq : (mat == 1) ? Wk : Wv;
    const float* bias = (mat == 0) ? bq : (mat == 1) ? bk : bv;
    const float osc = (mat == 0) ? SCALE_LOG2 : 1.0f;
    const int r0 = blockIdx.x * 64;

    {
        const int o = t >> 1;
        const int i0 = (t & 1) * 64;
        for (int jj = 0; jj < 8; ++jj) {
            floatx4 w0 = *reinterpret_cast<const floatx4*>(W + o * 128 + i0 + jj * 8);
            floatx4 w1 = *reinterpret_cast<const floatx4*>(W + o * 128 + i0 + jj * 8 + 4);
            half8_t h;
            h[0]=(_Float16)w0[0]; h[1]=(_Float16)w0[1]; h[2]=(_Float16)w0[2]; h[3]=(_Float16)w0[3];
            h[4]=(_Float16)w1[0]; h[5]=(_Float16)w1[1]; h[6]=(_Float16)w1[2]; h[7]=(_Float16)w1[3];
            *reinterpret_cast<half8_t*>(&Ws[o * 136 + i0 + jj * 8]) = h;
        }
    }
    {
        const int row = t >> 2;
        const int c0 = (t & 3) * 32;
        for (int jj = 0; jj < 4; ++jj) {
            floatx4 w0 = *reinterpret_cast<const floatx4*>(x + (size_t)(r0 + row) * 128 + c0 + jj * 8);
            floatx4 w1 = *reinterpret_cast<const floatx4*>(x + (size_t)(r0 + row) * 128 + c0 + jj * 8 + 4);
            half8_t h;
            h[0]=(_Float16)w0[0]; h[1]=(_Float16)w0[1]; h[2]=(_Float16)w0[2]; h[3]=(_Float16)w0[3];
            h[4]=(_Float16)w1[0]; h[5]=(_Float16)w1[1]; h[6]=(_Float16)w1[2]; h[7]=(_Float16)w1[3];
            *reinterpret_cast<half8_t*>(&xs[row * 136 + c0 + jj * 8]) = h;
        }
    }
    __syncthreads();

    const int w = t >> 6;
    const int lane = t & 63;
    const int lo = lane & 15, hi = lane >> 4;

    floatx4 acc[8] = {};
    for (int dc = 0; dc < 4; ++dc) {
        half8_t a8 = *reinterpret_cast<const half8_t*>(&xs[(w * 16 + lo) * 136 + dc * 32 + hi * 8]);
        for (int ot = 0; ot < 8; ++ot) {
            half8_t b8 = *reinterpret_cast<const half8_t*>(&Ws[(ot * 16 + lo) * 136 + dc * 32 + hi * 8]);
            acc[ot] = __builtin_amdgcn_mfma_f32_16x16x32_f16(a8, b8, acc[ot], 0, 0, 0);
        }
    }
    __syncthreads();

    float bb[8];
    for (int ot = 0; ot < 8; ++ot) bb[ot] = bias[ot * 16 + lo];

    if (mat < 2) {
        _Float16* ol = xs;
        for (int ot = 0; ot < 8; ++ot)
            for (int r = 0; r < 4; ++r)
                ol[(w * 16 + hi * 4 + r) * 136 + ot * 16 + lo] = (_Float16)((acc[ot][r] + bb[ot]) * osc);
        __syncthreads();
        _Float16* dst = (mat == 0) ? qf : kf;
        for (int i = 0; i < 4; ++i) {
            int c = t + 256 * i;
            int row = c >> 4, p = c & 15;
            half8_t v = *reinterpret_cast<const half8_t*>(&ol[row * 136 + p * 8]);
            *reinterpret_cast<half8_t*>(dst + (size_t)(r0 + row) * 128 + p * 8) = v;
        }
    } else {
        _Float16* vl = Ws;  // [128][72]
        for (int ot = 0; ot < 8; ++ot)
            for (int r = 0; r < 4; ++r)
                vl[(ot * 16 + lo) * 72 + w * 16 + hi * 4 + r] = (_Float16)(acc[ot][r] + bb[ot]);
        __syncthreads();
        const int b = r0 >> 12, tl0 = r0 & 4095;
        for (int i = 0; i < 4; ++i) {
            int c = t + 256 * i;
            int d = c >> 3, p = c & 7;
            half8_t v = *reinterpret_cast<const half8_t*>(&vl[d * 72 + p * 8]);
            *reinterpret_cast<half8_t*>(vt + ((size_t)(b * 128 + d)) * 4096 + tl0 + p * 8) = v;
        }
    }
}

// ---------------- flash attention: barrier-free per-wave-private pipeline ----------------
// 256 blocks x 512 threads = 8 waves: 2 q-groups (32 q as 2x16) x 4 kv-splits (16 kv).
// kv tile = 64. EACH WAVE owns a private 18KB LDS region: K 2x4KB (16 rows x 256B,
// swizzled, via global_load_lds) + V 2x5KB (128 d-rows x 32B padded to 40B -> PV
// ds_read_b64 conflict-free). A wave only ever reads its OWN staged data ->
// ZERO __syncthreads() in the main loop; ordering is one s_waitcnt vmcnt(8) per tile
// (prev tile's K-DMA) + compiler register-dependency waits for the V regs.
__global__ __launch_bounds__(512, 1) void attn_kernel(
    const _Float16* __restrict__ qf, const _Float16* __restrict__ kf,
    const _Float16* __restrict__ vt, float* __restrict__ out)
{
    __shared__ __align__(16) char smem[147456];   // 8 waves x 18432B private

    const int tid = threadIdx.x;
    const int w = tid >> 6, lane = tid & 63;
    const int lo = lane & 15, hi = lane >> 4;
    const int qg = w & 1, ksp = w >> 1;

    // XCD-aware swizzle: 32 consecutive wg per XCD -> one batch's K/V per XCD L2
    const int bx = blockIdx.x;
    const int wg = (bx & 7) * 32 + (bx >> 3);
    const int b = wg >> 6;
    const int q0 = (wg & 63) * 64;

    const char* kbc = (const char*)(kf + (size_t)b * T_SEQ * 128);
    const char* vbc = (const char*)(vt + (size_t)b * 128 * T_SEQ);

    char* const wbase = smem + w * 18432;
    char* const Kb0 = wbase;            // K buffers: 4096B each
    char* const Kb1 = wbase + 4096;
    char* const Vb0 = wbase + 8192;     // V buffers: 128 x 40B = 5120B each
    char* const Vb1 = wbase + 13312;

    // K staging: private 16 rows x 256B. LDS[r][slot] = K[ksp*16+r][slot ^ (r&7)].
    int koff[4], kdst[4];
#pragma unroll
    for (int r = 0; r < 4; ++r) {
        int rl = r * 4 + (lane >> 4);
        koff[r] = (ksp * 16 + rl) * 256 + (((lane & 15) ^ (rl & 7)) << 4);
        kdst[r] = r * 1024 + lane * 16;
    }
    // V staging: lane loads uint4 at d=(lane>>1)+32i, 16B half h=lane&1; LDS row pad 40B.
    int vsrc[4], vdst[4];
#pragma unroll
    for (int i = 0; i < 4; ++i) {
        int d = (lane >> 1) + 32 * i;
        vsrc[i] = d * (T_SEQ * 2) + ksp * 32 + (lane & 1) * 16;
        vdst[i] = d * 40 + (lane & 1) * 16;
    }
    // LDS read offsets (loop-invariant)
    int kro[4];
#pragma unroll
    for (int dc = 0; dc < 4; ++dc)
        kro[dc] = lo * 256 + (((dc * 4 + hi) ^ (lo & 7)) << 4);
    int vro[8];
#pragma unroll
    for (int dt = 0; dt < 8; ++dt)
        vro[dt] = (dt * 16 + lo) * 40 + hi * 8;   // banks 10*lo+2*hi: conflict-free

    // Q fragments (pre-scaled by log2(e)/sqrt(D)): d-enum dc*32+hi*8+j matches K-side
    half8_t qfA[4], qfB[4];
    {
        const _Float16* qa = qf + ((size_t)b * T_SEQ + q0 + qg * 32 + lo) * 128;
        const _Float16* qb = qa + 16 * 128;
#pragma unroll
        for (int dc = 0; dc < 4; ++dc) {
            qfA[dc] = *reinterpret_cast<const half8_t*>(qa + dc * 32 + hi * 8);
            qfB[dc] = *reinterpret_cast<const half8_t*>(qb + dc * 32 + hi * 8);
        }
    }

    floatx4 accA[8] = {}, accB[8] = {};
    float mA = -1e30f, mB = -1e30f, lA = 0.f, lB = 0.f;   // l is LANE-PARTIAL
    half4_t paA = {}, paB = {};                           // P of previous tile

#define VSTORE(VBUF, VR) do {                                                          \
    _Pragma("unroll")                                                                  \
    for (int i = 0; i < 4; ++i) {                                                      \
        *reinterpret_cast<uint2*>((VBUF) + vdst[i]) = make_uint2(VR[i].x, VR[i].y);    \
        *reinterpret_cast<uint2*>((VBUF) + vdst[i] + 8) = make_uint2(VR[i].z, VR[i].w);\
    }                                                                                  \
} while (0)

    // prologue: K(0) -> Kb0 (issued first!), V(0) -> regs -> Vb0
#pragma unroll
    for (int r = 0; r < 4; ++r) gload16(kbc + koff[r], Kb0 + kdst[r]);
    {
        uint4 vr[4];
#pragma unroll
        for (int i = 0; i < 4; ++i) vr[i] = *reinterpret_cast<const uint4*>(vbc + vsrc[i]);
        VSTORE(Vb0, vr);   // compiler's vr-wait drains K(0) too (older)
    }

    // Per tile t: [issue K(t+1) FIRST, then V(t+1)->regs] [vmcnt(8): K(t) ready]
    //   [QK(t)] [lane-local defer-max] [PV(t-1) from VOTH] [V regs -> VOTH] [pa(t)]
    // V(t-1) and V(t+1) share a buffer (same parity); read-then-write is same-wave
    // program order. No barriers.
#define TILE(T0, KCUR, KNXT, VOTH, PF, DOPREV) do {                                    \
    uint4 vr[4];                                                                       \
    if (PF) {                                                                          \
        const char* ks = kbc + (size_t)((T0) + 1) * 16384;                             \
        _Pragma("unroll")                                                              \
        for (int r = 0; r < 4; ++r) gload16(ks + koff[r], (KNXT) + kdst[r]);           \
        const char* vs = vbc + (size_t)((T0) + 1) * 128;                               \
        _Pragma("unroll")                                                              \
        for (int i = 0; i < 4; ++i)                                                    \
            vr[i] = *reinterpret_cast<const uint4*>(vs + vsrc[i]);                     \
        asm volatile("s_waitcnt vmcnt(8)" ::: "memory");                               \
    } else {                                                                           \
        asm volatile("s_waitcnt vmcnt(0)" ::: "memory");                               \
    }                                                                                  \
    __builtin_amdgcn_sched_barrier(0);                                                 \
    floatx4 sA = {0.f,0.f,0.f,0.f}, sB = {0.f,0.f,0.f,0.f};                            \
    __builtin_amdgcn_s_setprio(1);                                                     \
    _Pragma("unroll")                                                                  \
    for (int dc = 0; dc < 4; ++dc) {                                                   \
        half8_t kf8 = *reinterpret_cast<const half8_t*>((KCUR) + kro[dc]);             \
        sA = __builtin_amdgcn_mfma_f32_16x16x32_f16(kf8, qfA[dc], sA, 0, 0, 0);        \
        sB = __builtin_amdgcn_mfma_f32_16x16x32_f16(kf8, qfB[dc], sB, 0, 0, 0);        \
    }                                                                                  \
    __builtin_amdgcn_s_setprio(0);                                                     \
    float mpA = fmaxf(fmaxf(sA[0], sA[1]), fmaxf(sA[2], sA[3]));                       \
    float mpB = fmaxf(fmaxf(sB[0], sB[1]), fmaxf(sB[2], sB[3]));                       \
    bool ok = (mpA <= mA + 4.0f) && (mpB <= mB + 4.0f);                                \
    if (!__all(ok)) {                                                                  \
        float ra = mpA, rb = mpB;                                                      \
        ra = fmaxf(ra, __shfl_xor(ra, 16)); ra = fmaxf(ra, __shfl_xor(ra, 32));        \
        rb = fmaxf(rb, __shfl_xor(rb, 16)); rb = fmaxf(rb, __shfl_xor(rb, 32));        \
        float nA = fmaxf(mA, ra), nB = fmaxf(mB, rb);                                  \
        float aA = exp2_raw(mA - nA), aB = exp2_raw(mB - nB);                          \
        lA *= aA; lB *= aB;                                                            \
        _Pragma("unroll")                                                              \
        for (int dt = 0; dt < 8; ++dt) { accA[dt] *= aA; accB[dt] *= aB; }             \
        mA = nA; mB = nB;                                                              \
    }                                                                                  \
    if (DOPREV) {                                                                      \
        __builtin_amdgcn_s_setprio(1);                                                 \
        _Pragma("unroll")                                                              \
        for (int dt = 0; dt < 8; ++dt) {                                               \
            half4_t vfr = *reinterpret_cast<const half4_t*>((VOTH) + vro[dt]);         \
            accA[dt] = __builtin_amdgcn_mfma_f32_16x16x16f16(vfr, paA, accA[dt], 0, 0, 0); \
            accB[dt] = __builtin_amdgcn_mfma_f32_16x16x16f16(vfr, paB, accB[dt], 0, 0, 0); \
        }                                                                              \
        __builtin_amdgcn_s_setprio(0);                                                 \
    }                                                                                  \
    if (PF) VSTORE(VOTH, vr);                                                          \
    {                                                                                  \
        float p0 = exp2_raw(sA[0] - mA), p1 = exp2_raw(sA[1] - mA);                    \
        float p2 = exp2_raw(sA[2] - mA), p3 = exp2_raw(sA[3] - mA);                    \
        lA += (p0 + p1) + (p2 + p3);                                                   \
        half2_t h0 = __builtin_bit_cast(half2_t, __builtin_amdgcn_cvt_pkrtz(p0, p1));  \
        half2_t h1 = __builtin_bit_cast(half2_t, __builtin_amdgcn_cvt_pkrtz(p2, p3));  \
        paA[0] = h0[0]; paA[1] = h0[1]; paA[2] = h1[0]; paA[3] = h1[1];                \
        p0 = exp2_raw(sB[0] - mB); p1 = exp2_raw(sB[1] - mB);                          \
        p2 = exp2_raw(sB[2] - mB); p3 = exp2_raw(sB[3] - mB);                          \
        lB += (p0 + p1) + (p2 + p3);                                                   \
        h0 = __builtin_bit_cast(half2_t, __builtin_amdgcn_cvt_pkrtz(p0, p1));          \
        h1 = __builtin_bit_cast(half2_t, __builtin_amdgcn_cvt_pkrtz(p2, p3));          \
        paB[0] = h0[0]; paB[1] = h0[1]; paB[2] = h1[0]; paB[3] = h1[1];                \
    }                                                                                  \
} while (0)

    // 64 tiles of 64 kv. K(t) in Kb[t&1]; V(t) in Vb[t&1].
    TILE(0, Kb0, Kb1, Vb1, 1, 0);
    for (int tt = 1; tt < 62; tt += 2) {
        TILE(tt,     Kb1, Kb0, Vb0, 1, 1);
        TILE(tt + 1, Kb0, Kb1, Vb1, 1, 1);
    }
    TILE(63, Kb1, Kb0, Vb0, 0, 1);
#undef TILE

    // epilogue: PV of tile 63 (V(63) in Vb1)
#pragma unroll
    for (int dt = 0; dt < 8; ++dt) {
        half4_t vfr = *reinterpret_cast<const half4_t*>(Vb1 + vro[dt]);
        accA[dt] = __builtin_amdgcn_mfma_f32_16x16x16f16(vfr, paA, accA[dt], 0, 0, 0);
        accB[dt] = __builtin_amdgcn_mfma_f32_16x16x16f16(vfr, paB, accB[dt], 0, 0, 0);
    }

    // reduce lane-partial l across hi-groups (once)
    lA += __shfl_xor(lA, 16); lA += __shfl_xor(lA, 32);
    lB += __shfl_xor(lB, 16); lB += __shfl_xor(lB, 32);

    // ---- merge 4 kv-splits (private regions dead; barriers fine here) ----
    float* red_m = reinterpret_cast<float*>(smem + 34816);   // [4][64]
    float* red_l = reinterpret_cast<float*>(smem + 35840);   // [4][64]
    const int rowA = qg * 32 + lo, rowB = qg * 32 + 16 + lo;
    __syncthreads();   // all waves done with compute before smem reuse
    if (hi == 0) {
        red_m[ksp * 64 + rowA] = mA; red_l[ksp * 64 + rowA] = lA;
        red_m[ksp * 64 + rowB] = mB; red_l[ksp * 64 + rowB] = lB;
    }
    __syncthreads();
    float facA, facB;
    {
        float M = -1e30f, L = 0.f;
#pragma unroll
        for (int s = 0; s < 4; ++s) M = fmaxf(M, red_m[s * 64 + rowA]);
#pragma unroll
        for (int s = 0; s < 4; ++s) L += red_l[s * 64 + rowA] * exp2_raw(red_m[s * 64 + rowA] - M);
        facA = exp2_raw(mA - M) / L;
        M = -1e30f; L = 0.f;
#pragma unroll
        for (int s = 0; s < 4; ++s) M = fmaxf(M, red_m[s * 64 + rowB]);
#pragma unroll
        for (int s = 0; s < 4; ++s) L += red_l[s * 64 + rowB] * exp2_raw(red_m[s * 64 + rowB] - M);
        facB = exp2_raw(mB - M) / L;
    }
    float* out_lds = reinterpret_cast<float*>(smem);  // [64][132] fp32 = 33792B
    for (int s = 0; s < 4; ++s) {
        if (ksp == s) {
#pragma unroll
            for (int dt = 0; dt < 8; ++dt)
#pragma unroll
                for (int r = 0; r < 4; ++r) {
                    int d = dt * 16 + hi * 4 + r;
                    float vA = accA[dt][r] * facA;
                    float vB = accB[dt][r] * facB;
                    float* pA = &out_lds[rowA * 132 + d];
                    float* pB = &out_lds[rowB * 132 + d];
                    if (s == 0) { *pA = vA; *pB = vB; }
                    else        { *pA += vA; *pB += vB; }
                }
        }
        __syncthreads();
    }
    {
        int row = tid >> 3, d0 = (tid & 7) * 16;
        float* op = out + ((size_t)b * T_SEQ + q0 + row) * 128 + d0;
#pragma unroll
        for (int j = 0; j < 4; ++j) {
            float4 v;
            v.x = out_lds[row * 132 + d0 + j * 4 + 0];
            v.y = out_lds[row * 132 + d0 + j * 4 + 1];
            v.z = out_lds[row * 132 + d0 + j * 4 + 2];
            v.w = out_lds[row * 132 + d0 + j * 4 + 3];
            *reinterpret_cast<float4*>(op + j * 4) = v;
        }
    }
}

extern "C" void kernel_launch(void* const* d_in, const int* in_sizes, int n_in,
                              void* d_out, int out_size, void* d_ws, size_t ws_size,
                              hipStream_t stream)
{
    (void)in_sizes; (void)n_in; (void)out_size; (void)ws_size;
    const float* x  = (const float*)d_in[0];
    const float* Wq = (const float*)d_in[1];
    const float* bq = (const float*)d_in[2];
    const float* Wk = (const float*)d_in[3];
    const float* bk = (const float*)d_in[4];
    const float* Wv = (const float*)d_in[5];
    const float* bv = (const float*)d_in[6];
    float* out = (float*)d_out;

    _Float16* qf = (_Float16*)d_ws;
    _Float16* kf = qf + (size_t)4 * T_SEQ * D_HEAD;
    _Float16* vt = kf + (size_t)4 * T_SEQ * D_HEAD;

    proj_kernel<<<dim3(256, 3), 256, 0, stream>>>(x, Wq, bq, Wk, bk, Wv, bv, qf, kf, vt);
    attn_kernel<<<dim3(256), 512, 0, stream>>>(qf, kf, vt, out);
}

// Round 12
// 101.675 us; speedup vs baseline: 2.1724x; 1.0002x over previous
//
#include <hip/hip_runtime.h>
#include <cstdint>

typedef _Float16 half2_t __attribute__((ext_vector_type(2)));
typedef _Float16 half4_t __attribute__((ext_vector_type(4)));
typedef _Float16 half8_t __attribute__((ext_vector_type(8)));
typedef float floatx4 __attribute__((ext_vector_type(4)));

#define T_SEQ 4096
#define D_HEAD 128
#define SCALE_LOG2 0.12751742526f  // log2(e)/sqrt(128), folded into q at proj time

__device__ __forceinline__ void gload16(const void* src, void* dst_lds) {
    using gptr_t = const __attribute__((address_space(1))) unsigned int*;
    using lptr_t = __attribute__((address_space(3))) unsigned int*;
    __builtin_amdgcn_global_load_lds((gptr_t)(uintptr_t)src,
                                     (lptr_t)(unsigned int)(uintptr_t)dst_lds, 16, 0, 0);
}

__device__ __forceinline__ float exp2_raw(float x) {
#if __has_builtin(__builtin_amdgcn_exp2f)
    return __builtin_amdgcn_exp2f(x);   // raw v_exp_f32
#else
    return exp2f(x);
#endif
}

// ---------------- QKV projection (MFMA f16, fp32 accumulate) ----------------
__global__ __launch_bounds__(256) void proj_kernel(
    const float* __restrict__ x,
    const float* __restrict__ Wq, const float* __restrict__ bq,
    const float* __restrict__ Wk, const float* __restrict__ bk,
    const float* __restrict__ Wv, const float* __restrict__ bv,
    _Float16* __restrict__ qf, _Float16* __restrict__ kf, _Float16* __restrict__ vt)
{
    __shared__ __align__(16) _Float16 Ws[128 * 136];
    __shared__ __align__(16) _Float16 xs[64 * 136];

    const int t = threadIdx.x;
    const int mat = blockIdx.y;
    const float* W = (mat == 0) ? Wq : (mat == 1) ? Wk : Wv;
    const float* bias = (mat == 0) ? bq : (mat == 1) ? bk : bv;
    const float osc = (mat == 0) ? SCALE_LOG2 : 1.0f;
    const int r0 = blockIdx.x * 64;

    {
        const int o = t >> 1;
        const int i0 = (t & 1) * 64;
        for (int jj = 0; jj < 8; ++jj) {
            floatx4 w0 = *reinterpret_cast<const floatx4*>(W + o * 128 + i0 + jj * 8);
            floatx4 w1 = *reinterpret_cast<const floatx4*>(W + o * 128 + i0 + jj * 8 + 4);
            half8_t h;
            h[0]=(_Float16)w0[0]; h[1]=(_Float16)w0[1]; h[2]=(_Float16)w0[2]; h[3]=(_Float16)w0[3];
            h[4]=(_Float16)w1[0]; h[5]=(_Float16)w1[1]; h[6]=(_Float16)w1[2]; h[7]=(_Float16)w1[3];
            *reinterpret_cast<half8_t*>(&Ws[o * 136 + i0 + jj * 8]) = h;
        }
    }
    {
        const int row = t >> 2;
        const int c0 = (t & 3) * 32;
        for (int jj = 0; jj < 4; ++jj) {
            floatx4 w0 = *reinterpret_cast<const floatx4*>(x + (size_t)(r0 + row) * 128 + c0 + jj * 8);
            floatx4 w1 = *reinterpret_cast<const floatx4*>(x + (size_t)(r0 + row) * 128 + c0 + jj * 8 + 4);
            half8_t h;
            h[0]=(_Float16)w0[0]; h[1]=(_Float16)w0[1]; h[2]=(_Float16)w0[2]; h[3]=(_Float16)w0[3];
            h[4]=(_Float16)w1[0]; h[5]=(_Float16)w1[1]; h[6]=(_Float16)w1[2]; h[7]=(_Float16)w1[3];
            *reinterpret_cast<half8_t*>(&xs[row * 136 + c0 + jj * 8]) = h;
        }
    }
    __syncthreads();

    const int w = t >> 6;
    const int lane = t & 63;
    const int lo = lane & 15, hi = lane >> 4;

    floatx4 acc[8] = {};
    for (int dc = 0; dc < 4; ++dc) {
        half8_t a8 = *reinterpret_cast<const half8_t*>(&xs[(w * 16 + lo) * 136 + dc * 32 + hi * 8]);
        for (int ot = 0; ot < 8; ++ot) {
            half8_t b8 = *reinterpret_cast<const half8_t*>(&Ws[(ot * 16 + lo) * 136 + dc * 32 + hi * 8]);
            acc[ot] = __builtin_amdgcn_mfma_f32_16x16x32_f16(a8, b8, acc[ot], 0, 0, 0);
        }
    }
    __syncthreads();

    float bb[8];
    for (int ot = 0; ot < 8; ++ot) bb[ot] = bias[ot * 16 + lo];

    if (mat < 2) {
        _Float16* ol = xs;
        for (int ot = 0; ot < 8; ++ot)
            for (int r = 0; r < 4; ++r)
                ol[(w * 16 + hi * 4 + r) * 136 + ot * 16 + lo] = (_Float16)((acc[ot][r] + bb[ot]) * osc);
        __syncthreads();
        _Float16* dst = (mat == 0) ? qf : kf;
        for (int i = 0; i < 4; ++i) {
            int c = t + 256 * i;
            int row = c >> 4, p = c & 15;
            half8_t v = *reinterpret_cast<const half8_t*>(&ol[row * 136 + p * 8]);
            *reinterpret_cast<half8_t*>(dst + (size_t)(r0 + row) * 128 + p * 8) = v;
        }
    } else {
        _Float16* vl = Ws;  // [128][72]
        for (int ot = 0; ot < 8; ++ot)
            for (int r = 0; r < 4; ++r)
                vl[(ot * 16 + lo) * 72 + w * 16 + hi * 4 + r] = (_Float16)(acc[ot][r] + bb[ot]);
        __syncthreads();
        const int b = r0 >> 12, tl0 = r0 & 4095;
        for (int i = 0; i < 4; ++i) {
            int c = t + 256 * i;
            int d = c >> 3, p = c & 7;
            half8_t v = *reinterpret_cast<const half8_t*>(&vl[d * 72 + p * 8]);
            *reinterpret_cast<half8_t*>(vt + ((size_t)(b * 128 + d)) * 4096 + tl0 + p * 8) = v;
        }
    }
}

// ---------------- flash attention: barrier-free per-wave-private pipeline ----------------
// 256 blocks x 512 threads = 8 waves: 2 q-groups (32 q as 2x16) x 4 kv-splits (16 kv).
// kv tile = 64. EACH WAVE owns a private 18KB LDS region: K 2x4KB (16 rows x 256B,
// swizzled, via global_load_lds) + V 2x5KB (128 d-rows x 32B padded to 40B -> PV
// ds_read_b64 conflict-free). A wave only ever reads its OWN staged data ->
// ZERO __syncthreads() in the main loop; ordering is one s_waitcnt vmcnt(8) per tile
// (prev tile's K-DMA) + compiler register-dependency waits for the V regs.
__global__ __launch_bounds__(512, 1) void attn_kernel(
    const _Float16* __restrict__ qf, const _Float16* __restrict__ kf,
    const _Float16* __restrict__ vt, float* __restrict__ out)
{
    __shared__ __align__(16) char smem[147456];   // 8 waves x 18432B private

    const int tid = threadIdx.x;
    const int w = tid >> 6, lane = tid & 63;
    const int lo = lane & 15, hi = lane >> 4;
    const int qg = w & 1, ksp = w >> 1;

    // XCD-aware swizzle: 32 consecutive wg per XCD -> one batch's K/V per XCD L2
    const int bx = blockIdx.x;
    const int wg = (bx & 7) * 32 + (bx >> 3);
    const int b = wg >> 6;
    const int q0 = (wg & 63) * 64;

    const char* kbc = (const char*)(kf + (size_t)b * T_SEQ * 128);
    const char* vbc = (const char*)(vt + (size_t)b * 128 * T_SEQ);

    char* const wbase = smem + w * 18432;
    char* const Kb0 = wbase;            // K buffers: 4096B each
    char* const Kb1 = wbase + 4096;
    char* const Vb0 = wbase + 8192;     // V buffers: 128 x 40B = 5120B each
    char* const Vb1 = wbase + 13312;

    // K staging: private 16 rows x 256B. LDS[r][slot] = K[ksp*16+r][slot ^ (r&7)].
    int koff[4], kdst[4];
#pragma unroll
    for (int r = 0; r < 4; ++r) {
        int rl = r * 4 + (lane >> 4);
        koff[r] = (ksp * 16 + rl) * 256 + (((lane & 15) ^ (rl & 7)) << 4);
        kdst[r] = r * 1024 + lane * 16;
    }
    // V staging: lane loads uint4 at d=(lane>>1)+32i, 16B half h=lane&1; LDS row pad 40B.
    int vsrc[4], vdst[4];
#pragma unroll
    for (int i = 0; i < 4; ++i) {
        int d = (lane >> 1) + 32 * i;
        vsrc[i] = d * (T_SEQ * 2) + ksp * 32 + (lane & 1) * 16;
        vdst[i] = d * 40 + (lane & 1) * 16;
    }
    // LDS read offsets (loop-invariant)
    int kro[4];
#pragma unroll
    for (int dc = 0; dc < 4; ++dc)
        kro[dc] = lo * 256 + (((dc * 4 + hi) ^ (lo & 7)) << 4);
    int vro[8];
#pragma unroll
    for (int dt = 0; dt < 8; ++dt)
        vro[dt] = (dt * 16 + lo) * 40 + hi * 8;   // banks 10*lo+2*hi: conflict-free

    // Q fragments (pre-scaled by log2(e)/sqrt(D)): d-enum dc*32+hi*8+j matches K-side
    half8_t qfA[4], qfB[4];
    {
        const _Float16* qa = qf + ((size_t)b * T_SEQ + q0 + qg * 32 + lo) * 128;
        const _Float16* qb = qa + 16 * 128;
#pragma unroll
        for (int dc = 0; dc < 4; ++dc) {
            qfA[dc] = *reinterpret_cast<const half8_t*>(qa + dc * 32 + hi * 8);
            qfB[dc] = *reinterpret_cast<const half8_t*>(qb + dc * 32 + hi * 8);
        }
    }

    floatx4 accA[8] = {}, accB[8] = {};
    float mA = -1e30f, mB = -1e30f, lA = 0.f, lB = 0.f;   // l is LANE-PARTIAL
    half4_t paA = {}, paB = {};                           // P of previous tile

#define VSTORE(VBUF, VR) do {                                                          \
    _Pragma("unroll")                                                                  \
    for (int i = 0; i < 4; ++i) {                                                      \
        *reinterpret_cast<uint2*>((VBUF) + vdst[i]) = make_uint2(VR[i].x, VR[i].y);    \
        *reinterpret_cast<uint2*>((VBUF) + vdst[i] + 8) = make_uint2(VR[i].z, VR[i].w);\
    }                                                                                  \
} while (0)

    // prologue: K(0) -> Kb0 (issued first!), V(0) -> regs -> Vb0
#pragma unroll
    for (int r = 0; r < 4; ++r) gload16(kbc + koff[r], Kb0 + kdst[r]);
    {
        uint4 vr[4];
#pragma unroll
        for (int i = 0; i < 4; ++i) vr[i] = *reinterpret_cast<const uint4*>(vbc + vsrc[i]);
        VSTORE(Vb0, vr);   // compiler's vr-wait drains K(0) too (older)
    }

    // Per tile t: [issue K(t+1) FIRST, then V(t+1)->regs] [vmcnt(8): K(t) ready]
    //   [QK(t)] [lane-local defer-max] [PV(t-1) from VOTH] [V regs -> VOTH] [pa(t)]
    // V(t-1) and V(t+1) share a buffer (same parity); read-then-write is same-wave
    // program order. No barriers.
#define TILE(T0, KCUR, KNXT, VOTH, PF, DOPREV) do {                                    \
    uint4 vr[4];                                                                       \
    if (PF) {                                                                          \
        const char* ks = kbc + (size_t)((T0) + 1) * 16384;                             \
        _Pragma("unroll")                                                              \
        for (int r = 0; r < 4; ++r) gload16(ks + koff[r], (KNXT) + kdst[r]);           \
        const char* vs = vbc + (size_t)((T0) + 1) * 128;                               \
        _Pragma("unroll")                                                              \
        for (int i = 0; i < 4; ++i)                                                    \
            vr[i] = *reinterpret_cast<const uint4*>(vs + vsrc[i]);                     \
        asm volatile("s_waitcnt vmcnt(8)" ::: "memory");                               \
    } else {                                                                           \
        asm volatile("s_waitcnt vmcnt(0)" ::: "memory");                               \
    }                                                                                  \
    __builtin_amdgcn_sched_barrier(0);                                                 \
    floatx4 sA = {0.f,0.f,0.f,0.f}, sB = {0.f,0.f,0.f,0.f};                            \
    __builtin_amdgcn_s_setprio(1);                                                     \
    _Pragma("unroll")                                                                  \
    for (int dc = 0; dc < 4; ++dc) {                                                   \
        half8_t kf8 = *reinterpret_cast<const half8_t*>((KCUR) + kro[dc]);             \
        sA = __builtin_amdgcn_mfma_f32_16x16x32_f16(kf8, qfA[dc], sA, 0, 0, 0);        \
        sB = __builtin_amdgcn_mfma_f32_16x16x32_f16(kf8, qfB[dc], sB, 0, 0, 0);        \
    }                                                                                  \
    __builtin_amdgcn_s_setprio(0);                                                     \
    float mpA = fmaxf(fmaxf(sA[0], sA[1]), fmaxf(sA[2], sA[3]));                       \
    float mpB = fmaxf(fmaxf(sB[0], sB[1]), fmaxf(sB[2], sB[3]));                       \
    bool ok = (mpA <= mA + 4.0f) && (mpB <= mB + 4.0f);                                \
    if (!__all(ok)) {                                                                  \
        float ra = mpA, rb = mpB;                                                      \
        ra = fmaxf(ra, __shfl_xor(ra, 16)); ra = fmaxf(ra, __shfl_xor(ra, 32));        \
        rb = fmaxf(rb, __shfl_xor(rb, 16)); rb = fmaxf(rb, __shfl_xor(rb, 32));        \
        float nA = fmaxf(mA, ra), nB = fmaxf(mB, rb);                                  \
        float aA = exp2_raw(mA - nA), aB = exp2_raw(mB - nB);                          \
        lA *= aA; lB *= aB;                                                            \
        _Pragma("unroll")                                                              \
        for (int dt = 0; dt < 8; ++dt) { accA[dt] *= aA; accB[dt] *= aB; }             \
        mA = nA; mB = nB;                                                              \
    }                                                                                  \
    if (DOPREV) {                                                                      \
        __builtin_amdgcn_s_setprio(1);                                                 \
        _Pragma("unroll")                                                              \
        for (int dt = 0; dt < 8; ++dt) {                                               \
            half4_t vfr = *reinterpret_cast<const half4_t*>((VOTH) + vro[dt]);         \
            accA[dt] = __builtin_amdgcn_mfma_f32_16x16x16f16(vfr, paA, accA[dt], 0, 0, 0); \
            accB[dt] = __builtin_amdgcn_mfma_f32_16x16x16f16(vfr, paB, accB[dt], 0, 0, 0); \
        }                                                                              \
        __builtin_amdgcn_s_setprio(0);                                                 \
    }                                                                                  \
    if (PF) VSTORE(VOTH, vr);                                                          \
    {                                                                                  \
        float p0 = exp2_raw(sA[0] - mA), p1 = exp2_raw(sA[1] - mA);                    \
        float p2 = exp2_raw(sA[2] - mA), p3 = exp2_raw(sA[3] - mA);                    \
        lA += (p0 + p1) + (p2 + p3);                                                   \
        half2_t h0 = __builtin_bit_cast(half2_t, __builtin_amdgcn_cvt_pkrtz(p0, p1));  \
        half2_t h1 = __builtin_bit_cast(half2_t, __builtin_amdgcn_cvt_pkrtz(p2, p3));  \
        paA[0] = h0[0]; paA[1] = h0[1]; paA[2] = h1[0]; paA[3] = h1[1];                \
        p0 = exp2_raw(sB[0] - mB); p1 = exp2_raw(sB[1] - mB);                          \
        p2 = exp2_raw(sB[2] - mB); p3 = exp2_raw(sB[3] - mB);                          \
        lB += (p0 + p1) + (p2 + p3);                                                   \
        h0 = __builtin_bit_cast(half2_t, __builtin_amdgcn_cvt_pkrtz(p0, p1));          \
        h1 = __builtin_bit_cast(half2_t, __builtin_amdgcn_cvt_pkrtz(p2, p3));          \
        paB[0] = h0[0]; paB[1] = h0[1]; paB[2] = h1[0]; paB[3] = h1[1];                \
    }                                                                                  \
} while (0)

    // 64 tiles of 64 kv. K(t) in Kb[t&1]; V(t) in Vb[t&1].
    TILE(0, Kb0, Kb1, Vb1, 1, 0);
    for (int tt = 1; tt < 62; tt += 2) {
        TILE(tt,     Kb1, Kb0, Vb0, 1, 1);
        TILE(tt + 1, Kb0, Kb1, Vb1, 1, 1);
    }
    TILE(63, Kb1, Kb0, Vb0, 0, 1);
#undef TILE

    // epilogue: PV of tile 63 (V(63) in Vb1)
#pragma unroll
    for (int dt = 0; dt < 8; ++dt) {
        half4_t vfr = *reinterpret_cast<const half4_t*>(Vb1 + vro[dt]);
        accA[dt] = __builtin_amdgcn_mfma_f32_16x16x16f16(vfr, paA, accA[dt], 0, 0, 0);
        accB[dt] = __builtin_amdgcn_mfma_f32_16x16x16f16(vfr, paB, accB[dt], 0, 0, 0);
    }

    // reduce lane-partial l across hi-groups (once)
    lA += __shfl_xor(lA, 16); lA += __shfl_xor(lA, 32);
    lB += __shfl_xor(lB, 16); lB += __shfl_xor(lB, 32);

    // ---- merge 4 kv-splits (private regions dead; barriers fine here) ----
    float* red_m = reinterpret_cast<float*>(smem + 34816);   // [4][64]
    float* red_l = reinterpret_cast<float*>(smem + 35840);   // [4][64]
    const int rowA = qg * 32 + lo, rowB = qg * 32 + 16 + lo;
    __syncthreads();   // all waves done with compute before smem reuse
    if (hi == 0) {
        red_m[ksp * 64 + rowA] = mA; red_l[ksp * 64 + rowA] = lA;
        red_m[ksp * 64 + rowB] = mB; red_l[ksp * 64 + rowB] = lB;
    }
    __syncthreads();
    float facA, facB;
    {
        float M = -1e30f, L = 0.f;
#pragma unroll
        for (int s = 0; s < 4; ++s) M = fmaxf(M, red_m[s * 64 + rowA]);
#pragma unroll
        for (int s = 0; s < 4; ++s) L += red_l[s * 64 + rowA] * exp2_raw(red_m[s * 64 + rowA] - M);
        facA = exp2_raw(mA - M) / L;
        M = -1e30f; L = 0.f;
#pragma unroll
        for (int s = 0; s < 4; ++s) M = fmaxf(M, red_m[s * 64 + rowB]);
#pragma unroll
        for (int s = 0; s < 4; ++s) L += red_l[s * 64 + rowB] * exp2_raw(red_m[s * 64 + rowB] - M);
        facB = exp2_raw(mB - M) / L;
    }
    float* out_lds = reinterpret_cast<float*>(smem);  // [64][132] fp32 = 33792B
    for (int s = 0; s < 4; ++s) {
        if (ksp == s) {
#pragma unroll
            for (int dt = 0; dt < 8; ++dt)
#pragma unroll
                for (int r = 0; r < 4; ++r) {
                    int d = dt * 16 + hi * 4 + r;
                    float vA = accA[dt][r] * facA;
                    float vB = accB[dt][r] * facB;
                    float* pA = &out_lds[rowA * 132 + d];
                    float* pB = &out_lds[rowB * 132 + d];
                    if (s == 0) { *pA = vA; *pB = vB; }
                    else        { *pA += vA; *pB += vB; }
                }
        }
        __syncthreads();
    }
    {
        int row = tid >> 3, d0 = (tid & 7) * 16;
        float* op = out + ((size_t)b * T_SEQ + q0 + row) * 128 + d0;
#pragma unroll
        for (int j = 0; j < 4; ++j) {
            float4 v;
            v.x = out_lds[row * 132 + d0 + j * 4 + 0];
            v.y = out_lds[row * 132 + d0 + j * 4 + 1];
            v.z = out_lds[row * 132 + d0 + j * 4 + 2];
            v.w = out_lds[row * 132 + d0 + j * 4 + 3];
            *reinterpret_cast<float4*>(op + j * 4) = v;
        }
    }
}

extern "C" void kernel_launch(void* const* d_in, const int* in_sizes, int n_in,
                              void* d_out, int out_size, void* d_ws, size_t ws_size,
                              hipStream_t stream)
{
    (void)in_sizes; (void)n_in; (void)out_size; (void)ws_size;
    const float* x  = (const float*)d_in[0];
    const float* Wq = (const float*)d_in[1];
    const float* bq = (const float*)d_in[2];
    const float* Wk = (const float*)d_in[3];
    const float* bk = (const float*)d_in[4];
    const float* Wv = (const float*)d_in[5];
    const float* bv = (const float*)d_in[6];
    float* out = (float*)d_out;

    _Float16* qf = (_Float16*)d_ws;
    _Float16* kf = qf + (size_t)4 * T_SEQ * D_HEAD;
    _Float16* vt = kf + (size_t)4 * T_SEQ * D_HEAD;

    proj_kernel<<<dim3(256, 3), 256, 0, stream>>>(x, Wq, bq, Wk, bk, Wv, bv, qf, kf, vt);
    attn_kernel<<<dim3(256), 512, 0, stream>>>(qf, kf, vt, out);
}

// Round 13
// 101.499 us; speedup vs baseline: 2.1762x; 1.0017x over previous
//
#include <hip/hip_runtime.h>
#include <cstdint>

typedef _Float16 half2_t __attribute__((ext_vector_type(2)));
typedef _Float16 half4_t __attribute__((ext_vector_type(4)));
typedef _Float16 half8_t __attribute__((ext_vector_type(8)));
typedef float floatx4 __attribute__((ext_vector_type(4)));

#define T_SEQ 4096
#define D_HEAD 128
#define SCALE_LOG2 0.12751742526f  // log2(e)/sqrt(128), folded into q at proj time

__device__ __forceinline__ void gload16(const void* src, void* dst_lds) {
    using gptr_t = const __attribute__((address_space(1))) unsigned int*;
    using lptr_t = __attribute__((address_space(3))) unsigned int*;
    __builtin_amdgcn_global_load_lds((gptr_t)(uintptr_t)src,
                                     (lptr_t)(unsigned int)(uintptr_t)dst_lds, 16, 0, 0);
}

__device__ __forceinline__ float exp2_raw(float x) {
#if __has_builtin(__builtin_amdgcn_exp2f)
    return __builtin_amdgcn_exp2f(x);   // raw v_exp_f32
#else
    return exp2f(x);
#endif
}

// ---------------- QKV projection (MFMA f16, fp32 accumulate) ----------------
__global__ __launch_bounds__(256) void proj_kernel(
    const float* __restrict__ x,
    const float* __restrict__ Wq, const float* __restrict__ bq,
    const float* __restrict__ Wk, const float* __restrict__ bk,
    const float* __restrict__ Wv, const float* __restrict__ bv,
    _Float16* __restrict__ qf, _Float16* __restrict__ kf, _Float16* __restrict__ vt)
{
    __shared__ __align__(16) _Float16 Ws[128 * 136];
    __shared__ __align__(16) _Float16 xs[64 * 136];

    const int t = threadIdx.x;
    const int mat = blockIdx.y;
    const float* W = (mat == 0) ? Wq : (mat == 1) ? Wk : Wv;
    const float* bias = (mat == 0) ? bq : (mat == 1) ? bk : bv;
    const float osc = (mat == 0) ? SCALE_LOG2 : 1.0f;
    const int r0 = blockIdx.x * 64;

    {
        const int o = t >> 1;
        const int i0 = (t & 1) * 64;
        for (int jj = 0; jj < 8; ++jj) {
            floatx4 w0 = *reinterpret_cast<const floatx4*>(W + o * 128 + i0 + jj * 8);
            floatx4 w1 = *reinterpret_cast<const floatx4*>(W + o * 128 + i0 + jj * 8 + 4);
            half8_t h;
            h[0]=(_Float16)w0[0]; h[1]=(_Float16)w0[1]; h[2]=(_Float16)w0[2]; h[3]=(_Float16)w0[3];
            h[4]=(_Float16)w1[0]; h[5]=(_Float16)w1[1]; h[6]=(_Float16)w1[2]; h[7]=(_Float16)w1[3];
            *reinterpret_cast<half8_t*>(&Ws[o * 136 + i0 + jj * 8]) = h;
        }
    }
    {
        const int row = t >> 2;
        const int c0 = (t & 3) * 32;
        for (int jj = 0; jj < 4; ++jj) {
            floatx4 w0 = *reinterpret_cast<const floatx4*>(x + (size_t)(r0 + row) * 128 + c0 + jj * 8);
            floatx4 w1 = *reinterpret_cast<const floatx4*>(x + (size_t)(r0 + row) * 128 + c0 + jj * 8 + 4);
            half8_t h;
            h[0]=(_Float16)w0[0]; h[1]=(_Float16)w0[1]; h[2]=(_Float16)w0[2]; h[3]=(_Float16)w0[3];
            h[4]=(_Float16)w1[0]; h[5]=(_Float16)w1[1]; h[6]=(_Float16)w1[2]; h[7]=(_Float16)w1[3];
            *reinterpret_cast<half8_t*>(&xs[row * 136 + c0 + jj * 8]) = h;
        }
    }
    __syncthreads();

    const int w = t >> 6;
    const int lane = t & 63;
    const int lo = lane & 15, hi = lane >> 4;

    floatx4 acc[8] = {};
    for (int dc = 0; dc < 4; ++dc) {
        half8_t a8 = *reinterpret_cast<const half8_t*>(&xs[(w * 16 + lo) * 136 + dc * 32 + hi * 8]);
        for (int ot = 0; ot < 8; ++ot) {
            half8_t b8 = *reinterpret_cast<const half8_t*>(&Ws[(ot * 16 + lo) * 136 + dc * 32 + hi * 8]);
            acc[ot] = __builtin_amdgcn_mfma_f32_16x16x32_f16(a8, b8, acc[ot], 0, 0, 0);
        }
    }
    __syncthreads();

    float bb[8];
    for (int ot = 0; ot < 8; ++ot) bb[ot] = bias[ot * 16 + lo];

    if (mat < 2) {
        _Float16* ol = xs;
        for (int ot = 0; ot < 8; ++ot)
            for (int r = 0; r < 4; ++r)
                ol[(w * 16 + hi * 4 + r) * 136 + ot * 16 + lo] = (_Float16)((acc[ot][r] + bb[ot]) * osc);
        __syncthreads();
        _Float16* dst = (mat == 0) ? qf : kf;
        for (int i = 0; i < 4; ++i) {
            int c = t + 256 * i;
            int row = c >> 4, p = c & 15;
            half8_t v = *reinterpret_cast<const half8_t*>(&ol[row * 136 + p * 8]);
            *reinterpret_cast<half8_t*>(dst + (size_t)(r0 + row) * 128 + p * 8) = v;
        }
    } else {
        _Float16* vl = Ws;  // [128][72]
        for (int ot = 0; ot < 8; ++ot)
            for (int r = 0; r < 4; ++r)
                vl[(ot * 16 + lo) * 72 + w * 16 + hi * 4 + r] = (_Float16)(acc[ot][r] + bb[ot]);
        __syncthreads();
        const int b = r0 >> 12, tl0 = r0 & 4095;
        for (int i = 0; i < 4; ++i) {
            int c = t + 256 * i;
            int d = c >> 3, p = c & 7;
            half8_t v = *reinterpret_cast<const half8_t*>(&vl[d * 72 + p * 8]);
            *reinterpret_cast<half8_t*>(vt + ((size_t)(b * 128 + d)) * 4096 + tl0 + p * 8) = v;
        }
    }
}

// ---------------- flash attention: barrier-free per-wave-private pipeline ----------------
// 256 blocks x 512 threads = 8 waves: 2 q-groups (32 q as 2x16) x 4 kv-splits (16 kv).
// kv tile = 64. EACH WAVE owns a private 18KB LDS region: K 2x4KB (16 rows x 256B,
// swizzled, via global_load_lds) + V 2x5KB (128 d-rows x 32B padded to 40B -> PV
// ds_read_b64 conflict-free). A wave only ever reads its OWN staged data ->
// ZERO __syncthreads() in the main loop; ordering is one s_waitcnt vmcnt(8) per tile
// (prev tile's K-DMA) + compiler register-dependency waits for the V regs.
__global__ __launch_bounds__(512, 1) void attn_kernel(
    const _Float16* __restrict__ qf, const _Float16* __restrict__ kf,
    const _Float16* __restrict__ vt, float* __restrict__ out)
{
    __shared__ __align__(16) char smem[147456];   // 8 waves x 18432B private

    const int tid = threadIdx.x;
    const int w = tid >> 6, lane = tid & 63;
    const int lo = lane & 15, hi = lane >> 4;
    const int qg = w & 1, ksp = w >> 1;

    // XCD-aware swizzle: 32 consecutive wg per XCD -> one batch's K/V per XCD L2
    const int bx = blockIdx.x;
    const int wg = (bx & 7) * 32 + (bx >> 3);
    const int b = wg >> 6;
    const int q0 = (wg & 63) * 64;

    const char* kbc = (const char*)(kf + (size_t)b * T_SEQ * 128);
    const char* vbc = (const char*)(vt + (size_t)b * 128 * T_SEQ);

    char* const wbase = smem + w * 18432;
    char* const Kb0 = wbase;            // K buffers: 4096B each
    char* const Kb1 = wbase + 4096;
    char* const Vb0 = wbase + 8192;     // V buffers: 128 x 40B = 5120B each
    char* const Vb1 = wbase + 13312;

    // K staging: private 16 rows x 256B. LDS[r][slot] = K[ksp*16+r][slot ^ (r&7)].
    int koff[4], kdst[4];
#pragma unroll
    for (int r = 0; r < 4; ++r) {
        int rl = r * 4 + (lane >> 4);
        koff[r] = (ksp * 16 + rl) * 256 + (((lane & 15) ^ (rl & 7)) << 4);
        kdst[r] = r * 1024 + lane * 16;
    }
    // V staging: lane loads uint4 at d=(lane>>1)+32i, 16B half h=lane&1; LDS row pad 40B.
    int vsrc[4], vdst[4];
#pragma unroll
    for (int i = 0; i < 4; ++i) {
        int d = (lane >> 1) + 32 * i;
        vsrc[i] = d * (T_SEQ * 2) + ksp * 32 + (lane & 1) * 16;
        vdst[i] = d * 40 + (lane & 1) * 16;
    }
    // LDS read offsets (loop-invariant)
    int kro[4];
#pragma unroll
    for (int dc = 0; dc < 4; ++dc)
        kro[dc] = lo * 256 + (((dc * 4 + hi) ^ (lo & 7)) << 4);
    int vro[8];
#pragma unroll
    for (int dt = 0; dt < 8; ++dt)
        vro[dt] = (dt * 16 + lo) * 40 + hi * 8;   // banks 10*lo+2*hi: conflict-free

    // Q fragments (pre-scaled by log2(e)/sqrt(D)): d-enum dc*32+hi*8+j matches K-side
    half8_t qfA[4], qfB[4];
    {
        const _Float16* qa = qf + ((size_t)b * T_SEQ + q0 + qg * 32 + lo) * 128;
        const _Float16* qb = qa + 16 * 128;
#pragma unroll
        for (int dc = 0; dc < 4; ++dc) {
            qfA[dc] = *reinterpret_cast<const half8_t*>(qa + dc * 32 + hi * 8);
            qfB[dc] = *reinterpret_cast<const half8_t*>(qb + dc * 32 + hi * 8);
        }
    }

    floatx4 accA[8] = {}, accB[8] = {};
    float mA = -1e30f, mB = -1e30f, lA = 0.f, lB = 0.f;   // l is LANE-PARTIAL
    half4_t paA = {}, paB = {};                           // P of previous tile

#define VSTORE(VBUF, VR) do {                                                          \
    _Pragma("unroll")                                                                  \
    for (int i = 0; i < 4; ++i) {                                                      \
        *reinterpret_cast<uint2*>((VBUF) + vdst[i]) = make_uint2(VR[i].x, VR[i].y);    \
        *reinterpret_cast<uint2*>((VBUF) + vdst[i] + 8) = make_uint2(VR[i].z, VR[i].w);\
    }                                                                                  \
} while (0)

    // prologue: K(0) -> Kb0 (issued first!), V(0) -> regs -> Vb0
#pragma unroll
    for (int r = 0; r < 4; ++r) gload16(kbc + koff[r], Kb0 + kdst[r]);
    {
        uint4 vr[4];
#pragma unroll
        for (int i = 0; i < 4; ++i) vr[i] = *reinterpret_cast<const uint4*>(vbc + vsrc[i]);
        VSTORE(Vb0, vr);   // compiler's vr-wait drains K(0) too (older)
    }

    // Per tile t: [issue K(t+1) FIRST, then V(t+1)->regs] [vmcnt(8): K(t) ready]
    //   [QK(t)] [lane-local defer-max] [PV(t-1) from VOTH] [V regs -> VOTH] [pa(t)]
    // V(t-1) and V(t+1) share a buffer (same parity); read-then-write is same-wave
    // program order. No barriers.
#define TILE(T0, KCUR, KNXT, VOTH, PF, DOPREV) do {                                    \
    uint4 vr[4];                                                                       \
    if (PF) {                                                                          \
        const char* ks = kbc + (size_t)((T0) + 1) * 16384;                             \
        _Pragma("unroll")                                                              \
        for (int r = 0; r < 4; ++r) gload16(ks + koff[r], (KNXT) + kdst[r]);           \
        const char* vs = vbc + (size_t)((T0) + 1) * 128;                               \
        _Pragma("unroll")                                                              \
        for (int i = 0; i < 4; ++i)                                                    \
            vr[i] = *reinterpret_cast<const uint4*>(vs + vsrc[i]);                     \
        asm volatile("s_waitcnt vmcnt(8)" ::: "memory");                               \
    } else {                                                                           \
        asm volatile("s_waitcnt vmcnt(0)" ::: "memory");                               \
    }                                                                                  \
    __builtin_amdgcn_sched_barrier(0);                                                 \
    floatx4 sA = {0.f,0.f,0.f,0.f}, sB = {0.f,0.f,0.f,0.f};                            \
    __builtin_amdgcn_s_setprio(1);                                                     \
    _Pragma("unroll")                                                                  \
    for (int dc = 0; dc < 4; ++dc) {                                                   \
        half8_t kf8 = *reinterpret_cast<const half8_t*>((KCUR) + kro[dc]);             \
        sA = __builtin_amdgcn_mfma_f32_16x16x32_f16(kf8, qfA[dc], sA, 0, 0, 0);        \
        sB = __builtin_amdgcn_mfma_f32_16x16x32_f16(kf8, qfB[dc], sB, 0, 0, 0);        \
    }                                                                                  \
    __builtin_amdgcn_s_setprio(0);                                                     \
    float mpA = fmaxf(fmaxf(sA[0], sA[1]), fmaxf(sA[2], sA[3]));                       \
    float mpB = fmaxf(fmaxf(sB[0], sB[1]), fmaxf(sB[2], sB[3]));                       \
    bool ok = (mpA <= mA + 4.0f) && (mpB <= mB + 4.0f);                                \
    if (!__all(ok)) {                                                                  \
        float ra = mpA, rb = mpB;                                                      \
        ra = fmaxf(ra, __shfl_xor(ra, 16)); ra = fmaxf(ra, __shfl_xor(ra, 32));        \
        rb = fmaxf(rb, __shfl_xor(rb, 16)); rb = fmaxf(rb, __shfl_xor(rb, 32));        \
        float nA = fmaxf(mA, ra), nB = fmaxf(mB, rb);                                  \
        float aA = exp2_raw(mA - nA), aB = exp2_raw(mB - nB);                          \
        lA *= aA; lB *= aB;                                                            \
        _Pragma("unroll")                                                              \
        for (int dt = 0; dt < 8; ++dt) { accA[dt] *= aA; accB[dt] *= aB; }             \
        mA = nA; mB = nB;                                                              \
    }                                                                                  \
    if (DOPREV) {                                                                      \
        __builtin_amdgcn_s_setprio(1);                                                 \
        _Pragma("unroll")                                                              \
        for (int dt = 0; dt < 8; ++dt) {                                               \
            half4_t vfr = *reinterpret_cast<const half4_t*>((VOTH) + vro[dt]);         \
            accA[dt] = __builtin_amdgcn_mfma_f32_16x16x16f16(vfr, paA, accA[dt], 0, 0, 0); \
            accB[dt] = __builtin_amdgcn_mfma_f32_16x16x16f16(vfr, paB, accB[dt], 0, 0, 0); \
        }                                                                              \
        __builtin_amdgcn_s_setprio(0);                                                 \
    }                                                                                  \
    if (PF) VSTORE(VOTH, vr);                                                          \
    {                                                                                  \
        float p0 = exp2_raw(sA[0] - mA), p1 = exp2_raw(sA[1] - mA);                    \
        float p2 = exp2_raw(sA[2] - mA), p3 = exp2_raw(sA[3] - mA);                    \
        lA += (p0 + p1) + (p2 + p3);                                                   \
        half2_t h0 = __builtin_bit_cast(half2_t, __builtin_amdgcn_cvt_pkrtz(p0, p1));  \
        half2_t h1 = __builtin_bit_cast(half2_t, __builtin_amdgcn_cvt_pkrtz(p2, p3));  \
        paA[0] = h0[0]; paA[1] = h0[1]; paA[2] = h1[0]; paA[3] = h1[1];                \
        p0 = exp2_raw(sB[0] - mB); p1 = exp2_raw(sB[1] - mB);                          \
        p2 = exp2_raw(sB[2] - mB); p3 = exp2_raw(sB[3] - mB);                          \
        lB += (p0 + p1) + (p2 + p3);                                                   \
        h0 = __builtin_bit_cast(half2_t, __builtin_amdgcn_cvt_pkrtz(p0, p1));          \
        h1 = __builtin_bit_cast(half2_t, __builtin_amdgcn_cvt_pkrtz(p2, p3));          \
        paB[0] = h0[0]; paB[1] = h0[1]; paB[2] = h1[0]; paB[3] = h1[1];                \
    }                                                                                  \
} while (0)

    // 64 tiles of 64 kv. K(t) in Kb[t&1]; V(t) in Vb[t&1].
    TILE(0, Kb0, Kb1, Vb1, 1, 0);
    for (int tt = 1; tt < 62; tt += 2) {
        TILE(tt,     Kb1, Kb0, Vb0, 1, 1);
        TILE(tt + 1, Kb0, Kb1, Vb1, 1, 1);
    }
    TILE(63, Kb1, Kb0, Vb0, 0, 1);
#undef TILE

    // epilogue: PV of tile 63 (V(63) in Vb1)
#pragma unroll
    for (int dt = 0; dt < 8; ++dt) {
        half4_t vfr = *reinterpret_cast<const half4_t*>(Vb1 + vro[dt]);
        accA[dt] = __builtin_amdgcn_mfma_f32_16x16x16f16(vfr, paA, accA[dt], 0, 0, 0);
        accB[dt] = __builtin_amdgcn_mfma_f32_16x16x16f16(vfr, paB, accB[dt], 0, 0, 0);
    }

    // reduce lane-partial l across hi-groups (once)
    lA += __shfl_xor(lA, 16); lA += __shfl_xor(lA, 32);
    lB += __shfl_xor(lB, 16); lB += __shfl_xor(lB, 32);

    // ---- merge 4 kv-splits (private regions dead; barriers fine here) ----
    float* red_m = reinterpret_cast<float*>(smem + 34816);   // [4][64]
    float* red_l = reinterpret_cast<float*>(smem + 35840);   // [4][64]
    const int rowA = qg * 32 + lo, rowB = qg * 32 + 16 + lo;
    __syncthreads();   // all waves done with compute before smem reuse
    if (hi == 0) {
        red_m[ksp * 64 + rowA] = mA; red_l[ksp * 64 + rowA] = lA;
        red_m[ksp * 64 + rowB] = mB; red_l[ksp * 64 + rowB] = lB;
    }
    __syncthreads();
    float facA, facB;
    {
        float M = -1e30f, L = 0.f;
#pragma unroll
        for (int s = 0; s < 4; ++s) M = fmaxf(M, red_m[s * 64 + rowA]);
#pragma unroll
        for (int s = 0; s < 4; ++s) L += red_l[s * 64 + rowA] * exp2_raw(red_m[s * 64 + rowA] - M);
        facA = exp2_raw(mA - M) / L;
        M = -1e30f; L = 0.f;
#pragma unroll
        for (int s = 0; s < 4; ++s) M = fmaxf(M, red_m[s * 64 + rowB]);
#pragma unroll
        for (int s = 0; s < 4; ++s) L += red_l[s * 64 + rowB] * exp2_raw(red_m[s * 64 + rowB] - M);
        facB = exp2_raw(mB - M) / L;
    }
    float* out_lds = reinterpret_cast<float*>(smem);  // [64][132] fp32 = 33792B
    for (int s = 0; s < 4; ++s) {
        if (ksp == s) {
#pragma unroll
            for (int dt = 0; dt < 8; ++dt)
#pragma unroll
                for (int r = 0; r < 4; ++r) {
                    int d = dt * 16 + hi * 4 + r;
                    float vA = accA[dt][r] * facA;
                    float vB = accB[dt][r] * facB;
                    float* pA = &out_lds[rowA * 132 + d];
                    float* pB = &out_lds[rowB * 132 + d];
                    if (s == 0) { *pA = vA; *pB = vB; }
                    else        { *pA += vA; *pB += vB; }
                }
        }
        __syncthreads();
    }
    {
        int row = tid >> 3, d0 = (tid & 7) * 16;
        float* op = out + ((size_t)b * T_SEQ + q0 + row) * 128 + d0;
#pragma unroll
        for (int j = 0; j < 4; ++j) {
            float4 v;
            v.x = out_lds[row * 132 + d0 + j * 4 + 0];
            v.y = out_lds[row * 132 + d0 + j * 4 + 1];
            v.z = out_lds[row * 132 + d0 + j * 4 + 2];
            v.w = out_lds[row * 132 + d0 + j * 4 + 3];
            *reinterpret_cast<float4*>(op + j * 4) = v;
        }
    }
}

extern "C" void kernel_launch(void* const* d_in, const int* in_sizes, int n_in,
                              void* d_out, int out_size, void* d_ws, size_t ws_size,
                              hipStream_t stream)
{
    (void)in_sizes; (void)n_in; (void)out_size; (void)ws_size;
    const float* x  = (const float*)d_in[0];
    const float* Wq = (const float*)d_in[1];
    const float* bq = (const float*)d_in[2];
    const float* Wk = (const float*)d_in[3];
    const float* bk = (const float*)d_in[4];
    const float* Wv = (const float*)d_in[5];
    const float* bv = (const float*)d_in[6];
    float* out = (float*)d_out;

    _Float16* qf = (_Float16*)d_ws;
    _Float16* kf = qf + (size_t)4 * T_SEQ * D_HEAD;
    _Float16* vt = kf + (size_t)4 * T_SEQ * D_HEAD;

    proj_kernel<<<dim3(256, 3), 256, 0, stream>>>(x, Wq, bq, Wk, bk, Wv, bv, qf, kf, vt);
    attn_kernel<<<dim3(256), 512, 0, stream>>>(qf, kf, vt, out);
}